// Round 1
// baseline (284.793 us; speedup 1.0000x reference)
//
#include <hip/hip_runtime.h>
#include <hip/hip_bf16.h>

typedef __attribute__((ext_vector_type(8))) short short8;
typedef __attribute__((ext_vector_type(4))) float f32x4;
typedef unsigned short u16;
typedef unsigned int u32;

static __device__ __forceinline__ u16 f2b(float f) {
  __hip_bfloat16 h = __float2bfloat16(f);
  return __builtin_bit_cast(u16, h);
}

// ---------------- conversion kernels ----------------

__global__ __launch_bounds__(256) void cvt_f32_to_bf16(const float4* __restrict__ in,
                                                       uint2* __restrict__ out, int n4) {
  int i = blockIdx.x * 256 + threadIdx.x;
  if (i < n4) {
    float4 v = in[i];
    uint2 o;
    o.x = (u32)f2b(v.x) | ((u32)f2b(v.y) << 16);
    o.y = (u32)f2b(v.z) | ((u32)f2b(v.w) << 16);
    out[i] = o;
  }
}

// out[c*R + r] = bf16(in[r*in_rs + col_off + c]); R,C multiples of 32
__global__ __launch_bounds__(256) void tcvt_f32_to_bf16(const float* __restrict__ in, int in_rs,
                                                        int col_off, u16* __restrict__ out,
                                                        int R, int C) {
  __shared__ u16 tile[32][33];
  int t = threadIdx.x, tx = t & 31, ty = t >> 5;
  int ctiles = C >> 5;
  int r0 = (blockIdx.x / ctiles) * 32, c0 = (blockIdx.x % ctiles) * 32;
#pragma unroll
  for (int i = 0; i < 4; ++i) {
    int r = r0 + ty + i * 8;
    tile[ty + i * 8][tx] = f2b(in[(size_t)r * in_rs + col_off + c0 + tx]);
  }
  __syncthreads();
#pragma unroll
  for (int i = 0; i < 4; ++i) {
    int c = c0 + ty + i * 8;
    out[(size_t)c * R + r0 + tx] = tile[tx][ty + i * 8];
  }
}

// K (4096 x 1024 bf16, rows = b*2048+l) -> Kt[b][h][d][l] (2,16,64,2048)
__global__ __launch_bounds__(256) void transpose_heads(const u16* __restrict__ in,
                                                       u16* __restrict__ out) {
  __shared__ u16 tile[32][33];
  int t = threadIdx.x, tx = t & 31, ty = t >> 5;
  int r0 = (blockIdx.x >> 5) * 32;  // 128 row-tiles
  int c0 = (blockIdx.x & 31) * 32;  // 32 col-tiles
#pragma unroll
  for (int i = 0; i < 4; ++i)
    tile[ty + i * 8][tx] = in[(size_t)(r0 + ty + i * 8) * 1024 + c0 + tx];
  __syncthreads();
  int r = r0 + tx;
  int b = r >> 11;
#pragma unroll
  for (int i = 0; i < 4; ++i) {
    int c = c0 + ty + i * 8;
    out[((size_t)(b * 1024 + c) << 11) + (r & 2047)] = tile[tx][ty + i * 8];
  }
}

// ---------------- GEMM: C[M][N] = A[M][K] * Bt[N][K]^T + bias ----------------
// 128x128 tile, BK=64, 4 waves (2x2), 16x16x32 bf16 MFMA, XOR-swizzled LDS.
template <bool OUT_F32>
__global__ __launch_bounds__(256) void gemm_bias(const u16* __restrict__ A,
                                                 const u16* __restrict__ Bt,
                                                 const float* __restrict__ bias,
                                                 void* __restrict__ Cp, int M, int N, int K) {
  __shared__ char lds[32768];  // A tile 16KB + B tile 16KB
  int tid = threadIdx.x, lane = tid & 63, wid = tid >> 6;
  int lr = lane & 15, lh = lane >> 4;
  int nb = N >> 7;
  int m0 = (blockIdx.x / nb) << 7, n0 = (blockIdx.x % nb) << 7;
  int wm = wid >> 1, wn = wid & 1;
  f32x4 acc[4][4] = {};
  int r_s = tid >> 3;           // 0..31
  int cb_s = (tid & 7) << 4;    // byte in 128B row
  const char* Ab = (const char*)A;
  const char* Bb = (const char*)Bt;
  for (int k0 = 0; k0 < K; k0 += 64) {
    uint4 av[4], bv[4];
#pragma unroll
    for (int i = 0; i < 4; ++i) {
      int row = i * 32 + r_s;
      av[i] = *(const uint4*)(Ab + ((size_t)(m0 + row) * K + k0) * 2 + cb_s);
      bv[i] = *(const uint4*)(Bb + ((size_t)(n0 + row) * K + k0) * 2 + cb_s);
    }
    __syncthreads();  // previous iteration's reads done
#pragma unroll
    for (int i = 0; i < 4; ++i) {
      int row = i * 32 + r_s;
      int dst = row * 128 + (cb_s ^ ((row & 7) << 4));
      *(uint4*)(lds + dst) = av[i];
      *(uint4*)(lds + 16384 + dst) = bv[i];
    }
    __syncthreads();
    short8 af[4][2], bfr[4][2];
#pragma unroll
    for (int mi = 0; mi < 4; ++mi)
#pragma unroll
      for (int ks = 0; ks < 2; ++ks) {
        int row = wm * 64 + mi * 16 + lr;
        af[mi][ks] = *(const short8*)(lds + row * 128 + ((ks * 64 + lh * 16) ^ ((row & 7) << 4)));
      }
#pragma unroll
    for (int ni = 0; ni < 4; ++ni)
#pragma unroll
      for (int ks = 0; ks < 2; ++ks) {
        int row = wn * 64 + ni * 16 + lr;
        bfr[ni][ks] =
            *(const short8*)(lds + 16384 + row * 128 + ((ks * 64 + lh * 16) ^ ((row & 7) << 4)));
      }
#pragma unroll
    for (int ks = 0; ks < 2; ++ks)
#pragma unroll
      for (int mi = 0; mi < 4; ++mi)
#pragma unroll
        for (int ni = 0; ni < 4; ++ni)
          acc[mi][ni] = __builtin_amdgcn_mfma_f32_16x16x32_bf16(af[mi][ks], bfr[ni][ks],
                                                                acc[mi][ni], 0, 0, 0);
  }
#pragma unroll
  for (int mi = 0; mi < 4; ++mi)
#pragma unroll
    for (int ni = 0; ni < 4; ++ni) {
      int col = n0 + wn * 64 + ni * 16 + lr;
      float bz = bias[col];
#pragma unroll
      for (int r = 0; r < 4; ++r) {
        int row = m0 + wm * 64 + mi * 16 + lh * 4 + r;
        float v = acc[mi][ni][r] + bz;
        if (OUT_F32)
          ((float*)Cp)[(size_t)row * N + col] = v;
        else
          ((u16*)Cp)[(size_t)row * N + col] = f2b(v);
      }
    }
}

// ---------------- flash attention, Q=K=V ----------------
// grid: b(2) x h(16) x qtile(16); 4 waves x 32 q-rows; KB=64 key tiles; online softmax (base 2).
__global__ __launch_bounds__(256) void flash_attn(const u16* __restrict__ Kb,
                                                  const u16* __restrict__ Kt,
                                                  u16* __restrict__ AO) {
  __shared__ u16 plds[4 * 32 * 64];  // per-wave 32x64 P tile, XOR-swizzled, 16KB
  const float S2 = 0.125f * 1.44269504088896340736f;  // 1/sqrt(64) * log2(e)
  int tid = threadIdx.x, lane = tid & 63, wid = tid >> 6;
  int lr = lane & 15, lh = lane >> 4;
  int bid = blockIdx.x;
  int qb = bid & 15, h = (bid >> 4) & 15, b = bid >> 8;
  int qbase = b * 2048 + qb * 128 + wid * 32;
  int hc = h * 64;
  short8 qfr[2][2];
#pragma unroll
  for (int qf = 0; qf < 2; ++qf)
#pragma unroll
    for (int ks = 0; ks < 2; ++ks)
      qfr[qf][ks] =
          *(const short8*)(Kb + (size_t)(qbase + qf * 16 + lr) * 1024 + hc + ks * 32 + lh * 8);
  f32x4 acc_o[2][4] = {};
  float mrow[2][4], lrow[2][4];
#pragma unroll
  for (int qf = 0; qf < 2; ++qf)
#pragma unroll
    for (int r = 0; r < 4; ++r) {
      mrow[qf][r] = -__builtin_inff();
      lrow[qf][r] = 0.f;
    }
  int wbase = wid * 32 * 64;  // u16 units
  for (int kt = 0; kt < 32; ++kt) {
    short8 kfr[4][2];
#pragma unroll
    for (int kf = 0; kf < 4; ++kf)
#pragma unroll
      for (int ks = 0; ks < 2; ++ks)
        kfr[kf][ks] = *(const short8*)(Kb + (size_t)(b * 2048 + kt * 64 + kf * 16 + lr) * 1024 +
                                       hc + ks * 32 + lh * 8);
    f32x4 s[2][4] = {};
#pragma unroll
    for (int ks = 0; ks < 2; ++ks)
#pragma unroll
      for (int qf = 0; qf < 2; ++qf)
#pragma unroll
        for (int kf = 0; kf < 4; ++kf)
          s[qf][kf] =
              __builtin_amdgcn_mfma_f32_16x16x32_bf16(qfr[qf][ks], kfr[kf][ks], s[qf][kf], 0, 0, 0);
    // online softmax + P -> LDS (bf16)
#pragma unroll
    for (int qf = 0; qf < 2; ++qf)
#pragma unroll
      for (int r = 0; r < 4; ++r) {
        float v0 = s[qf][0][r] * S2, v1 = s[qf][1][r] * S2;
        float v2 = s[qf][2][r] * S2, v3 = s[qf][3][r] * S2;
        float tm = fmaxf(fmaxf(v0, v1), fmaxf(v2, v3));
        tm = fmaxf(tm, __shfl_xor(tm, 1));
        tm = fmaxf(tm, __shfl_xor(tm, 2));
        tm = fmaxf(tm, __shfl_xor(tm, 4));
        tm = fmaxf(tm, __shfl_xor(tm, 8));
        float mo = mrow[qf][r];
        float mn = fmaxf(mo, tm);
        float scl = exp2f(mo - mn);
        float p0 = exp2f(v0 - mn), p1 = exp2f(v1 - mn);
        float p2 = exp2f(v2 - mn), p3 = exp2f(v3 - mn);
        float rs = p0 + p1 + p2 + p3;
        rs += __shfl_xor(rs, 1);
        rs += __shfl_xor(rs, 2);
        rs += __shfl_xor(rs, 4);
        rs += __shfl_xor(rs, 8);
        lrow[qf][r] = lrow[qf][r] * scl + rs;
        mrow[qf][r] = mn;
#pragma unroll
        for (int df = 0; df < 4; ++df) acc_o[qf][df] [r] *= scl;
        int row = qf * 16 + lh * 4 + r;
        int sw = (row & 7) << 4;  // byte-XOR
        int rb = wbase + row * 64;
        plds[rb + ((((0 * 16 + lr) * 2) ^ sw) >> 1)] = f2b(p0);
        plds[rb + ((((1 * 16 + lr) * 2) ^ sw) >> 1)] = f2b(p1);
        plds[rb + ((((2 * 16 + lr) * 2) ^ sw) >> 1)] = f2b(p2);
        plds[rb + ((((3 * 16 + lr) * 2) ^ sw) >> 1)] = f2b(p3);
      }
    __syncthreads();  // cross-lane P visibility (conservative round-0 fence)
    short8 pfr[2][2], vfr[4][2];
#pragma unroll
    for (int qf = 0; qf < 2; ++qf)
#pragma unroll
      for (int k2 = 0; k2 < 2; ++k2) {
        int row = qf * 16 + lr;
        int cb = (k2 * 64 + lh * 16) ^ ((row & 7) << 4);
        pfr[qf][k2] = *(const short8*)(plds + wbase + row * 64 + (cb >> 1));
      }
#pragma unroll
    for (int df = 0; df < 4; ++df)
#pragma unroll
      for (int k2 = 0; k2 < 2; ++k2)
        vfr[df][k2] = *(const short8*)(Kt + (size_t)((b * 16 + h) * 64 + df * 16 + lr) * 2048 +
                                       kt * 64 + k2 * 32 + lh * 8);
#pragma unroll
    for (int k2 = 0; k2 < 2; ++k2)
#pragma unroll
      for (int qf = 0; qf < 2; ++qf)
#pragma unroll
        for (int df = 0; df < 4; ++df)
          acc_o[qf][df] = __builtin_amdgcn_mfma_f32_16x16x32_bf16(pfr[qf][k2], vfr[df][k2],
                                                                  acc_o[qf][df], 0, 0, 0);
    __syncthreads();  // reads done before next tile's P writes
  }
#pragma unroll
  for (int qf = 0; qf < 2; ++qf)
#pragma unroll
    for (int r = 0; r < 4; ++r) {
      float inv = 1.f / lrow[qf][r];
      int row = qbase + qf * 16 + lh * 4 + r;
#pragma unroll
      for (int df = 0; df < 4; ++df)
        AO[(size_t)row * 1024 + hc + df * 16 + lr] = f2b(acc_o[qf][df][r] * inv);
    }
}

// ---------------- launch ----------------

extern "C" void kernel_launch(void* const* d_in, const int* in_sizes, int n_in, void* d_out,
                              int out_size, void* d_ws, size_t ws_size, hipStream_t stream) {
  const float* x = (const float*)d_in[0];
  const float* W_attn = (const float*)d_in[1];
  const float* b_attn = (const float*)d_in[2];
  const float* W_proj = (const float*)d_in[3];
  const float* b_proj = (const float*)d_in[4];
  float* out = (float*)d_out;
  char* ws = (char*)d_ws;
  // ws layout (bytes): xb/AO 8.4M | Kb 8.4M | Kt 8.4M | Wkt 2M | Wpt 2M  = ~29.4MB
  u16* xb = (u16*)(ws);
  u16* Kb = (u16*)(ws + 8388608);
  u16* Kt = (u16*)(ws + 16777216);
  u16* Wkt = (u16*)(ws + 25165824);
  u16* Wpt = (u16*)(ws + 27262976);

  cvt_f32_to_bf16<<<4096, 256, 0, stream>>>((const float4*)x, (uint2*)xb, 1048576);
  tcvt_f32_to_bf16<<<1024, 256, 0, stream>>>(W_attn, 3072, 1024, Wkt, 1024, 1024);
  tcvt_f32_to_bf16<<<1024, 256, 0, stream>>>(W_proj, 1024, 0, Wpt, 1024, 1024);
  // K = x * W_attn[:,1024:2048] + b_attn[1024:2048]  (bf16 out)
  gemm_bias<false><<<256, 256, 0, stream>>>(xb, Wkt, b_attn + 1024, (void*)Kb, 4096, 1024, 1024);
  transpose_heads<<<4096, 256, 0, stream>>>(Kb, Kt);
  u16* AO = xb;  // xb dead after GEMM1; reuse as attention output
  flash_attn<<<512, 256, 0, stream>>>(Kb, Kt, AO);
  // out = AO * W_proj + b_proj  (f32 out)
  gemm_bias<true><<<256, 256, 0, stream>>>(AO, Wpt, b_proj, (void*)out, 4096, 1024, 1024);
}